// Round 18
// baseline (63.836 us; speedup 1.0000x reference)
//
#include <hip/hip_runtime.h>

typedef __bf16 bf16x8 __attribute__((ext_vector_type(8)));
typedef float f32x4 __attribute__((ext_vector_type(4)));
typedef unsigned short u16x4 __attribute__((ext_vector_type(4)));
typedef unsigned int u32x4 __attribute__((ext_vector_type(4)));

#define LDA 72    // bf16 row pitch (144 B): 16B-aligned rows

template <int N> struct Int { static constexpr int value = N; };

__device__ __forceinline__ unsigned short f2bf(float f) {
  __bf16 b = (__bf16)f;                      // hardware RTNE v_cvt
  return __builtin_bit_cast(unsigned short, b);
}

__device__ __forceinline__ u16x4 pack4(f32x4 v) {
  u16x4 r;
  r[0] = f2bf(v[0]); r[1] = f2bf(v[1]); r[2] = f2bf(v[2]); r[3] = f2bf(v[3]);
  return r;
}

__device__ __forceinline__ bf16x8 frag8(const unsigned short* p) {
  typedef unsigned short u16x8v __attribute__((ext_vector_type(8)));
  return __builtin_bit_cast(bf16x8, *reinterpret_cast<const u16x8v*>(p));
}

#define MFMA(a, b, c) __builtin_amdgcn_mfma_f32_16x16x32_bf16(a, b, c, 0, 0, 0)

// ---------------------------------------------------------------------------
// In-register C-frag -> A/B-frag conversion (validated permlane butterfly).
// Input C-frag rows become the output k-dim; lane column is preserved.
// ---------------------------------------------------------------------------
__device__ __forceinline__ void cfrag2bfrag(const f32x4 v[4], bf16x8 out[2]) {
  unsigned O[4][2];
  #pragma unroll
  for (int si = 0; si < 4; ++si) {
    u16x4 p = pack4(v[si]);
    O[si][0] = (unsigned)p[0] | ((unsigned)p[1] << 16);
    O[si][1] = (unsigned)p[2] | ((unsigned)p[3] << 16);
  }
  unsigned H[2][2][2];
  #pragma unroll
  for (int s1 = 0; s1 < 2; ++s1)
    #pragma unroll
    for (int d = 0; d < 2; ++d) {
      auto r = __builtin_amdgcn_permlane32_swap(O[2 * s1][d], O[2 * s1 + 1][d], false, false);
      H[s1][0][d] = r[0];
      H[s1][1][d] = r[1];
    }
  #pragma unroll
  for (int e1 = 0; e1 < 2; ++e1) {
    auto r0 = __builtin_amdgcn_permlane16_swap(H[e1][0][0], H[e1][1][0], false, false);
    auto r1 = __builtin_amdgcn_permlane16_swap(H[e1][0][1], H[e1][1][1], false, false);
    u32x4 f;
    f[0] = r0[0]; f[1] = r1[0]; f[2] = r0[1]; f[3] = r1[1];
    out[e1] = __builtin_bit_cast(bf16x8, f);
  }
}

// ---------------------------------------------------------------------------
// Fuse + pack (unchanged): t=0: M_h = Wq Wk^T * 0.125*log2e; t=1: N_h = Wv Wp_h.
// ---------------------------------------------------------------------------
__global__ __launch_bounds__(256) void fuse_pack(
    const float* __restrict__ Wq, const float* __restrict__ Wk,
    const float* __restrict__ Wv, const float* __restrict__ Wp,
    unsigned short* __restrict__ wf) {
  __shared__ float A[64 * 65];
  __shared__ float B[64 * 65];
  const int blk = blockIdx.x;           // 0..15
  const int t = blk >> 3, h = blk & 7;
  const int tid = threadIdx.x;
  const float* Asrc = (t ? Wv : Wq) + h * 4096;
  const float* Bsrc = (t ? Wp : Wk) + h * 4096;
  for (int i = tid; i < 4096; i += 256) {
    A[(i >> 6) * 65 + (i & 63)] = Asrc[i];
    B[(i >> 6) * 65 + (i & 63)] = Bsrc[i];
  }
  __syncthreads();
  unsigned short* dst = wf + blk * 4096;
  for (int o = 0; o < 16; ++o) {
    int idx = o * 256 + tid;
    int k = idx >> 6, n = idx & 63;
    float s = 0.f;
    if (t == 0) {
      for (int d = 0; d < 64; ++d) s += A[k * 65 + d] * B[n * 65 + d];
      s *= 0.18033688f;                 // 0.125 * log2(e)
    } else {
      for (int d = 0; d < 64; ++d) s += A[k * 65 + d] * B[d * 65 + n];
    }
    int kk = k >> 5, i = k & 7, lg = (k >> 3) & 3, si = n >> 4, l15 = n & 15;
    dst[((kk * 4 + si) * 64 + lg * 16 + l15) * 8 + i] = f2bf(s);
  }
}

// ---------------------------------------------------------------------------
// Main kernel: 256 threads = 4 waves; TWO WAVES PER BATCH split by mt
// column-tiles (mg=0: mt {0,3}; mg=1: mt {1,2}). Per head:
//   G = M^T X^T (own mt cols only)  : 16 MFMA
//   S = X G (causal)                : 10 MFMA -> in-reg softmax -> pA
//   Y^T = X^T P^T (reassociation!)  : 12 MFMA   [out = (P X) N == P (X N)]
//   out += Y N                      : 16 MFMA
// 54 MFMA/wave/head — NO duplicated work between the wave pair (R17's Z=XN
// recompute, 16 MFMA + 2 butterflies, eliminated). X^T frags come from a
// transposed LDS copy (XsT), read contiguously per head. Zero barriers
// after staging; each wave owns disjoint output rows.
// ---------------------------------------------------------------------------
__global__ __launch_bounds__(256, 4) void mha_fwd(
    const float* __restrict__ x, const unsigned short* __restrict__ wf,
    const float* __restrict__ bproj, float* __restrict__ out) {
  __shared__ __attribute__((aligned(16))) unsigned short Xs[2][64 * LDA];
  __shared__ __attribute__((aligned(16))) unsigned short XsT[2][64 * LDA];

  const int tid  = threadIdx.x;
  const int lane = tid & 63;
  const int w    = tid >> 6;
  const int bt   = w >> 1;           // batch within block
  const int mg   = w & 1;            // mt-group: 0 -> {0,3}, 1 -> {1,2}
  const int l15  = lane & 15;
  const int g    = lane >> 4;
  const int kcol = 8 * g;

  // ---- stage 2 batches: row-major Xs AND transposed XsT (bf16) ----
  const float* xb = x + (size_t)blockIdx.x * 8192;
  #pragma unroll
  for (int it = 0; it < 8; ++it) {
    int idx = it * 1024 + tid * 4;
    float4 v = *reinterpret_cast<const float4*>(xb + idx);
    f32x4 vv = {v.x, v.y, v.z, v.w};
    int sb = idx >> 12, rem = idx & 4095;
    int r = rem >> 6, c0 = rem & 63;
    u16x4 pk = pack4(vv);
    *reinterpret_cast<u16x4*>(&Xs[sb][r * LDA + c0]) = pk;
    #pragma unroll
    for (int j = 0; j < 4; ++j)
      XsT[sb][(c0 + j) * LDA + r] = pk[j];   // transpose (prologue-only)
  }
  __syncthreads();  // the ONLY barrier

  // ---- hoist this wave's X into registers (dual-role A/B frags) ----
  bf16x8 xf[2][4];   // element X[t*16+l15][cc*32 + 8g + i]
  #pragma unroll
  for (int cc = 0; cc < 2; ++cc)
    #pragma unroll
    for (int t = 0; t < 4; ++t)
      xf[cc][t] = frag8(&Xs[bt][(t * 16 + l15) * LDA + cc * 32 + kcol]);

  // ---- persistent out C-frags for OUR two mt row-tiles, bias-init ----
  f32x4 oacc[2][4];
  #pragma unroll
  for (int nt = 0; nt < 4; ++nt) {
    float bias = bproj[nt * 16 + l15];
    f32x4 bv = {bias, bias, bias, bias};
    oacc[0][nt] = bv;
    oacc[1][nt] = bv;
  }

  #pragma unroll 1
  for (int h = 0; h < 8; ++h) {
    const unsigned short* mf = wf + h * 4096;          // M^T A-frags
    const unsigned short* nf = wf + 32768 + h * 4096;  // N  B-frags

    auto head_body = [&](auto MT0C, auto MT1C) {
      constexpr int MT0 = decltype(MT0C)::value;
      constexpr int MT1 = decltype(MT1C)::value;
      bf16x8 pA[2][2];  // [cc][lmt]  (lane = m, k = s)

      // ---- per-mt: G (stream Mf) -> butterfly -> S (causal) -> softmax -> pA ----
      auto gs = [&](auto MTC, int lmt) {
        constexpr int MT = decltype(MTC)::value;
        f32x4 gc[4] = {};
        #pragma unroll
        for (int kk = 0; kk < 2; ++kk)
          #pragma unroll
          for (int ct = 0; ct < 4; ++ct)
            gc[ct] = MFMA(frag8(&mf[(kk * 4 + ct) * 512 + lane * 8]), xf[kk][MT], gc[ct]);
        bf16x8 gB[2];
        cfrag2bfrag(gc, gB);

        f32x4 sc[4] = {};
        #pragma unroll
        for (int cc = 0; cc < 2; ++cc)
          #pragma unroll
          for (int st = 0; st < 4; ++st)
            if (st <= MT)
              sc[st] = MFMA(xf[cc][st], gB[cc], sc[st]);

        const int m = MT * 16 + l15;
        float sum = 0.f;
        #pragma unroll
        for (int st = 0; st < 4; ++st) {
          if (st < MT) {
            #pragma unroll
            for (int r = 0; r < 4; ++r) { float e = exp2f(sc[st][r]); sc[st][r] = e; sum += e; }
          } else if (st == MT) {
            #pragma unroll
            for (int r = 0; r < 4; ++r) {
              int s = st * 16 + 4 * g + r;
              float e = (s <= m) ? exp2f(sc[st][r]) : 0.f;
              sc[st][r] = e; sum += e;
            }
          }
        }
        sum += __shfl_xor(sum, 16);
        sum += __shfl_xor(sum, 32);
        float rinv = __builtin_amdgcn_rcpf(sum);
        #pragma unroll
        for (int st = 0; st < 4; ++st)
          if (st <= MT) sc[st] *= rinv;
        bf16x8 o2[2];
        cfrag2bfrag(sc, o2);
        pA[0][lmt] = o2[0]; pA[1][lmt] = o2[1];
      };
      gs(Int<MT0>{}, 0);
      gs(Int<MT1>{}, 1);

      // ---- per-mt: Y^T = X^T P^T (causal cc-skip) -> butterfly -> out += Y N ----
      auto ypv = [&](auto MTC, int lmt) {
        constexpr int MT = decltype(MTC)::value;
        f32x4 ytc[4] = {};
        #pragma unroll
        for (int ct = 0; ct < 4; ++ct) {
          bf16x8 xb0 = frag8(&XsT[bt][(ct * 16 + l15) * LDA + kcol]);
          ytc[ct] = MFMA(xb0, pA[0][lmt], ytc[ct]);
          if (MT >= 2) {
            bf16x8 xb1 = frag8(&XsT[bt][(ct * 16 + l15) * LDA + 32 + kcol]);
            ytc[ct] = MFMA(xb1, pA[1][lmt], ytc[ct]);
          }
        }
        bf16x8 yA[2];
        cfrag2bfrag(ytc, yA);
        #pragma unroll
        for (int nt = 0; nt < 4; ++nt) {
          oacc[lmt][nt] = MFMA(yA[0], frag8(&nf[nt * 512 + lane * 8]), oacc[lmt][nt]);
          oacc[lmt][nt] = MFMA(yA[1], frag8(&nf[(4 + nt) * 512 + lane * 8]), oacc[lmt][nt]);
        }
      };
      ypv(Int<MT0>{}, 0);
      ypv(Int<MT1>{}, 1);
    };

    if (mg == 0) head_body(Int<0>{}, Int<3>{});
    else         head_body(Int<1>{}, Int<2>{});
  }

  // ---- store fp32 output: rows of our two mt tiles, all 64 cols ----
  const int mtv0 = mg ? 1 : 0;
  const int mtv1 = mg ? 2 : 3;
  float* ob = out + ((size_t)blockIdx.x * 2 + bt) * 4096;
  #pragma unroll
  for (int lmt = 0; lmt < 2; ++lmt) {
    int mt = lmt ? mtv1 : mtv0;
    #pragma unroll
    for (int r = 0; r < 4; ++r) {
      float* orow = ob + (mt * 16 + 4 * g + r) * 64;
      #pragma unroll
      for (int nt = 0; nt < 4; ++nt)
        orow[nt * 16 + l15] = oacc[lmt][nt][r];
    }
  }
}

extern "C" void kernel_launch(void* const* d_in, const int* in_sizes, int n_in,
                              void* d_out, int out_size, void* d_ws, size_t ws_size,
                              hipStream_t stream) {
  const float* x  = (const float*)d_in[0];
  const float* Wq = (const float*)d_in[1];
  const float* Wk = (const float*)d_in[2];
  const float* Wv = (const float*)d_in[3];
  const float* Wp = (const float*)d_in[4];
  const float* bp = (const float*)d_in[5];
  unsigned short* wf = (unsigned short*)d_ws;  // 65536 bf16 = 128 KB fused-weight frags

  fuse_pack<<<dim3(16), dim3(256), 0, stream>>>(Wq, Wk, Wv, Wp, wf);
  mha_fwd<<<dim3(1024), dim3(256), 0, stream>>>(x, wf, bp, (float*)d_out);
}

// Round 19
// 58.517 us; speedup vs baseline: 1.0909x; 1.0909x over previous
//
#include <hip/hip_runtime.h>

typedef __bf16 bf16x8 __attribute__((ext_vector_type(8)));
typedef float f32x4 __attribute__((ext_vector_type(4)));
typedef unsigned short u16x4 __attribute__((ext_vector_type(4)));
typedef unsigned short u16x8 __attribute__((ext_vector_type(8)));
typedef unsigned int u32x4 __attribute__((ext_vector_type(4)));

#define LDA 72    // bf16 row pitch (144 B): 16B-aligned rows

template <int N> struct Int { static constexpr int value = N; };

__device__ __forceinline__ unsigned short f2bf(float f) {
  __bf16 b = (__bf16)f;                      // hardware RTNE v_cvt
  return __builtin_bit_cast(unsigned short, b);
}

__device__ __forceinline__ u16x4 pack4(f32x4 v) {
  u16x4 r;
  r[0] = f2bf(v[0]); r[1] = f2bf(v[1]); r[2] = f2bf(v[2]); r[3] = f2bf(v[3]);
  return r;
}

__device__ __forceinline__ bf16x8 frag8(const unsigned short* p) {
  return __builtin_bit_cast(bf16x8, *reinterpret_cast<const u16x8*>(p));
}

#define MFMA(a, b, c) __builtin_amdgcn_mfma_f32_16x16x32_bf16(a, b, c, 0, 0, 0)

// ---------------------------------------------------------------------------
// In-register C-frag -> A/B-frag conversion (validated permlane butterfly).
// ---------------------------------------------------------------------------
__device__ __forceinline__ void cfrag2bfrag(const f32x4 v[4], bf16x8 out[2]) {
  unsigned O[4][2];
  #pragma unroll
  for (int si = 0; si < 4; ++si) {
    u16x4 p = pack4(v[si]);
    O[si][0] = (unsigned)p[0] | ((unsigned)p[1] << 16);
    O[si][1] = (unsigned)p[2] | ((unsigned)p[3] << 16);
  }
  unsigned H[2][2][2];
  #pragma unroll
  for (int s1 = 0; s1 < 2; ++s1)
    #pragma unroll
    for (int d = 0; d < 2; ++d) {
      auto r = __builtin_amdgcn_permlane32_swap(O[2 * s1][d], O[2 * s1 + 1][d], false, false);
      H[s1][0][d] = r[0];
      H[s1][1][d] = r[1];
    }
  #pragma unroll
  for (int e1 = 0; e1 < 2; ++e1) {
    auto r0 = __builtin_amdgcn_permlane16_swap(H[e1][0][0], H[e1][1][0], false, false);
    auto r1 = __builtin_amdgcn_permlane16_swap(H[e1][0][1], H[e1][1][1], false, false);
    u32x4 f;
    f[0] = r0[0]; f[1] = r1[0]; f[2] = r0[1]; f[3] = r1[1];
    out[e1] = __builtin_bit_cast(bf16x8, f);
  }
}

// ---------------------------------------------------------------------------
// Fuse + pack (unchanged): t=0: M_h = Wq Wk^T * 0.125*log2e; t=1: N_h = Wv Wp_h.
// ---------------------------------------------------------------------------
__global__ __launch_bounds__(256) void fuse_pack(
    const float* __restrict__ Wq, const float* __restrict__ Wk,
    const float* __restrict__ Wv, const float* __restrict__ Wp,
    unsigned short* __restrict__ wf) {
  __shared__ float A[64 * 65];
  __shared__ float B[64 * 65];
  const int blk = blockIdx.x;           // 0..15
  const int t = blk >> 3, h = blk & 7;
  const int tid = threadIdx.x;
  const float* Asrc = (t ? Wv : Wq) + h * 4096;
  const float* Bsrc = (t ? Wp : Wk) + h * 4096;
  for (int i = tid; i < 4096; i += 256) {
    A[(i >> 6) * 65 + (i & 63)] = Asrc[i];
    B[(i >> 6) * 65 + (i & 63)] = Bsrc[i];
  }
  __syncthreads();
  unsigned short* dst = wf + blk * 4096;
  for (int o = 0; o < 16; ++o) {
    int idx = o * 256 + tid;
    int k = idx >> 6, n = idx & 63;
    float s = 0.f;
    if (t == 0) {
      for (int d = 0; d < 64; ++d) s += A[k * 65 + d] * B[n * 65 + d];
      s *= 0.18033688f;                 // 0.125 * log2(e)
    } else {
      for (int d = 0; d < 64; ++d) s += A[k * 65 + d] * B[d * 65 + n];
    }
    int kk = k >> 5, i = k & 7, lg = (k >> 3) & 3, si = n >> 4, l15 = n & 15;
    dst[((kk * 4 + si) * 64 + lg * 16 + l15) * 8 + i] = f2bf(s);
  }
}

// ---------------------------------------------------------------------------
// Main kernel: 256 threads = 4 waves = 2 batches x 2 mt-groups
// (mg=0: mt {0,3}; mg=1: mt {1,2} — causally balanced). Per head per wave:
//   Z = X N for OWN two nt cols : 8 MFMA -> butterfly -> LDS exchange
//   G = M^T X^T (own mt)        : 16 MFMA -> butterfly -> gB
//   S = X G (causal)            : 10 MFMA -> in-reg softmax -> pA
//   barrier (Zs[h&1] ready; balanced waves)
//   out += P Z (4 nt, causal)   : 12 MFMA  (zB read back from LDS)
// 46 MFMA/wave/head, zero duplicated work (R17's 32-MFMA Z recompute cut to
// 8+exchange). Zs double-buffer aliases the dead Xs staging area (32 KB).
// ---------------------------------------------------------------------------
__global__ __launch_bounds__(256, 4) void mha_fwd(
    const float* __restrict__ x, const unsigned short* __restrict__ wf,
    const float* __restrict__ bproj, float* __restrict__ out) {
  __shared__ __attribute__((aligned(16))) unsigned char smem[32768];
  unsigned short* XsBase = reinterpret_cast<unsigned short*>(smem);  // [2][64*LDA], prologue only
  unsigned short* ZsBase = reinterpret_cast<unsigned short*>(smem);  // [bt][buf][8][64] x u16x8

  const int tid  = threadIdx.x;
  const int lane = tid & 63;
  const int w    = tid >> 6;
  const int bt   = w >> 1;           // batch within block
  const int mg   = w & 1;            // mt-group: 0 -> {0,3}, 1 -> {1,2}
  const int l15  = lane & 15;
  const int g    = lane >> 4;
  const int kcol = 8 * g;

  // ---- stage 2 batches (fp32 -> bf16, row-major [s][c]), coalesced ----
  const float* xb = x + (size_t)blockIdx.x * 8192;
  #pragma unroll
  for (int it = 0; it < 8; ++it) {
    int idx = it * 1024 + tid * 4;
    float4 v = *reinterpret_cast<const float4*>(xb + idx);
    f32x4 vv = {v.x, v.y, v.z, v.w};
    int sb = idx >> 12, rem = idx & 4095;
    *reinterpret_cast<u16x4*>(&XsBase[sb * (64 * LDA) + (rem >> 6) * LDA + (rem & 63)]) = pack4(vv);
  }
  __syncthreads();  // [P1] X staged

  // ---- hoist this wave's X into registers (dual-role A/B frags) ----
  bf16x8 xf[2][4];   // element X[t*16+l15][cc*32 + 8g + i]
  #pragma unroll
  for (int cc = 0; cc < 2; ++cc)
    #pragma unroll
    for (int t = 0; t < 4; ++t)
      xf[cc][t] = frag8(&XsBase[bt * (64 * LDA) + (t * 16 + l15) * LDA + cc * 32 + kcol]);
  __syncthreads();  // [P2] X reads done; smem becomes the Zs exchange buffer

  // ---- persistent out C-frags for OUR two mt row-tiles, bias-init ----
  f32x4 oacc[2][4];
  #pragma unroll
  for (int nt = 0; nt < 4; ++nt) {
    float bias = bproj[nt * 16 + l15];
    f32x4 bv = {bias, bias, bias, bias};
    oacc[0][nt] = bv;
    oacc[1][nt] = bv;
  }

  #pragma unroll 1
  for (int h = 0; h < 8; ++h) {
    const unsigned short* mf = wf + h * 4096;          // M^T A-frags
    const unsigned short* nf = wf + 32768 + h * 4096;  // N  B-frags
    unsigned short* zs = ZsBase + ((bt * 2 + (h & 1)) * 8) * 64 * 8;  // our batch, this buf

    auto head_body = [&](auto MT0C, auto MT1C) {
      constexpr int MT0 = decltype(MT0C)::value;
      constexpr int MT1 = decltype(MT1C)::value;

      // ---- Z = X N for OWN nt pair; butterfly; publish to LDS ----
      #pragma unroll
      for (int l = 0; l < 2; ++l) {
        const int ntg = 2 * mg + l;
        bf16x8 nf0 = frag8(&nf[ntg * 512 + lane * 8]);
        bf16x8 nf1 = frag8(&nf[(4 + ntg) * 512 + lane * 8]);
        f32x4 zc[4] = {};
        #pragma unroll
        for (int st = 0; st < 4; ++st) {
          zc[st] = MFMA(xf[0][st], nf0, zc[st]);
          zc[st] = MFMA(xf[1][st], nf1, zc[st]);
        }
        bf16x8 zb[2];
        cfrag2bfrag(zc, zb);
        #pragma unroll
        for (int cc = 0; cc < 2; ++cc)
          *reinterpret_cast<u16x8*>(&zs[((ntg * 2 + cc) * 64 + lane) * 8]) =
              __builtin_bit_cast(u16x8, zb[cc]);
      }

      // ---- per-mt: G (stream Mf) -> butterfly -> S (causal) -> softmax -> pA ----
      bf16x8 pA[2][2];  // [cc][lmt]  (lane = m, k = s)
      auto gs = [&](auto MTC, int lmt) {
        constexpr int MT = decltype(MTC)::value;
        f32x4 gc[4] = {};
        #pragma unroll
        for (int kk = 0; kk < 2; ++kk)
          #pragma unroll
          for (int ct = 0; ct < 4; ++ct)
            gc[ct] = MFMA(frag8(&mf[(kk * 4 + ct) * 512 + lane * 8]), xf[kk][MT], gc[ct]);
        bf16x8 gB[2];
        cfrag2bfrag(gc, gB);

        f32x4 sc[4] = {};
        #pragma unroll
        for (int cc = 0; cc < 2; ++cc)
          #pragma unroll
          for (int st = 0; st < 4; ++st)
            if (st <= MT)
              sc[st] = MFMA(xf[cc][st], gB[cc], sc[st]);

        const int m = MT * 16 + l15;
        float sum = 0.f;
        #pragma unroll
        for (int st = 0; st < 4; ++st) {
          if (st < MT) {
            #pragma unroll
            for (int r = 0; r < 4; ++r) { float e = exp2f(sc[st][r]); sc[st][r] = e; sum += e; }
          } else if (st == MT) {
            #pragma unroll
            for (int r = 0; r < 4; ++r) {
              int s = st * 16 + 4 * g + r;
              float e = (s <= m) ? exp2f(sc[st][r]) : 0.f;
              sc[st][r] = e; sum += e;
            }
          }
        }
        sum += __shfl_xor(sum, 16);
        sum += __shfl_xor(sum, 32);
        float rinv = __builtin_amdgcn_rcpf(sum);
        #pragma unroll
        for (int st = 0; st < 4; ++st)
          if (st <= MT) sc[st] *= rinv;
        bf16x8 o2[2];
        cfrag2bfrag(sc, o2);
        pA[0][lmt] = o2[0]; pA[1][lmt] = o2[1];
      };
      gs(Int<MT0>{}, 0);
      gs(Int<MT1>{}, 1);

      __syncthreads();  // [1/head] Zs[h&1] fully published (waves are balanced)

      // ---- out += P Z : read zB from LDS; causal cc-skip per mt ----
      #pragma unroll
      for (int nt = 0; nt < 4; ++nt) {
        bf16x8 zb0 = frag8(&zs[((nt * 2 + 0) * 64 + lane) * 8]);
        oacc[0][nt] = MFMA(pA[0][0], zb0, oacc[0][nt]);
        oacc[1][nt] = MFMA(pA[0][1], zb0, oacc[1][nt]);
        bf16x8 zb1 = frag8(&zs[((nt * 2 + 1) * 64 + lane) * 8]);
        if (MT0 >= 2) oacc[0][nt] = MFMA(pA[1][0], zb1, oacc[0][nt]);
        if (MT1 >= 2) oacc[1][nt] = MFMA(pA[1][1], zb1, oacc[1][nt]);
      }
    };

    if (mg == 0) head_body(Int<0>{}, Int<3>{});
    else         head_body(Int<1>{}, Int<2>{});
  }

  // ---- store fp32 output: rows of our two mt tiles, all 64 cols ----
  const int mtv0 = mg ? 1 : 0;
  const int mtv1 = mg ? 2 : 3;
  float* ob = out + ((size_t)blockIdx.x * 2 + bt) * 4096;
  #pragma unroll
  for (int lmt = 0; lmt < 2; ++lmt) {
    int mt = lmt ? mtv1 : mtv0;
    #pragma unroll
    for (int r = 0; r < 4; ++r) {
      float* orow = ob + (mt * 16 + 4 * g + r) * 64;
      #pragma unroll
      for (int nt = 0; nt < 4; ++nt)
        orow[nt * 16 + l15] = oacc[lmt][nt][r];
    }
  }
}

extern "C" void kernel_launch(void* const* d_in, const int* in_sizes, int n_in,
                              void* d_out, int out_size, void* d_ws, size_t ws_size,
                              hipStream_t stream) {
  const float* x  = (const float*)d_in[0];
  const float* Wq = (const float*)d_in[1];
  const float* Wk = (const float*)d_in[2];
  const float* Wv = (const float*)d_in[3];
  const float* Wp = (const float*)d_in[4];
  const float* bp = (const float*)d_in[5];
  unsigned short* wf = (unsigned short*)d_ws;  // 65536 bf16 = 128 KB fused-weight frags

  fuse_pack<<<dim3(16), dim3(256), 0, stream>>>(Wq, Wk, Wv, Wp, wf);
  mha_fwd<<<dim3(1024), dim3(256), 0, stream>>>(x, wf, bp, (float*)d_out);
}